// Round 1
// baseline (471.976 us; speedup 1.0000x reference)
//
#include <hip/hip_runtime.h>

// Problem constants (from reference):
//   segments: (8, 1, 512, 512) f32, values 0..63
//   downsample ::2 -> (8, 256, 256)
//   R=7, K_SIDE=15, 225 offsets, zero-padded OOB neighbors
//   out: (8, 225, 256, 256) f32 = 471.9 MB  -> write-BW bound (~78 us floor)

#define RAD 7
#define KS 15            // 2*RAD+1
#define HW 256           // downsampled H and W
#define IN_W 512
#define TILE_W (HW + 2 * RAD)   // 270
#define TILE_PITCH 272          // padded pitch (keeps rows 16B-aligned)

__global__ __launch_bounds__(256) void adj_kernel(const float* __restrict__ in,
                                                  float* __restrict__ out) {
    __shared__ float smem[KS][TILE_PITCH];

    const int y   = blockIdx.x;   // output row 0..255
    const int b   = blockIdx.y;   // batch 0..7
    const int tid = threadIdx.x;  // 0..255 -> output col x

    const float* inb = in + (size_t)b * (IN_W * IN_W);

    // Stage 15 downsampled rows (y-7 .. y+7) x 270 cols, zero-padded OOB.
    #pragma unroll
    for (int r = 0; r < KS; ++r) {
        const int gy = y - RAD + r;           // downsampled row index
        for (int c = tid; c < TILE_W; c += 256) {
            const int gx = c - RAD;           // downsampled col index
            float v = 0.0f;
            if ((unsigned)gy < HW && (unsigned)gx < HW) {
                v = inb[(size_t)(2 * gy) * IN_W + 2 * gx];
            }
            smem[r][c] = v;
        }
    }
    __syncthreads();

    const int x = tid;
    const float s = smem[RAD][x + RAD];       // this pixel's segment id

    // out[b][k][y][x], k = r*15 + dc, plane stride = 256*256
    float* op = out + (size_t)b * 225 * (HW * HW) + (size_t)y * HW + x;

    #pragma unroll
    for (int r = 0; r < KS; ++r) {
        #pragma unroll
        for (int dc = 0; dc < KS; ++dc) {
            const float n = smem[r][x + dc];  // neighbor at (dy=r-7, dx=dc-7)
            *op = (s == n) ? 1.0f : 0.0f;
            op += HW * HW;
        }
    }
}

extern "C" void kernel_launch(void* const* d_in, const int* in_sizes, int n_in,
                              void* d_out, int out_size, void* d_ws, size_t ws_size,
                              hipStream_t stream) {
    const float* segments = (const float*)d_in[0];
    float* out = (float*)d_out;
    dim3 grid(HW, 8);   // (y, b)
    dim3 block(256);
    adj_kernel<<<grid, block, 0, stream>>>(segments, out);
}

// Round 2
// 463.837 us; speedup vs baseline: 1.0175x; 1.0175x over previous
//
#include <hip/hip_runtime.h>

// segments: (8, 1, 512, 512) f32, values 0..63; downsample ::2 -> (8, 256, 256)
// R=7, K_SIDE=15, 225 offsets, zero-padded OOB neighbors
// out: (8, 225, 256, 256) f32 = 471.9 MB  -> write-BW floor ~75 us
//
// R2: float4 nontemporal stores (1 KB/wave-instr), register sliding window
// (5x ds_read_b128 per kernel-row instead of 15x ds_read_b32), waves split
// kernel rows r = wave + 4*j.

#define RAD 7
#define KS 15            // 2*RAD+1
#define HW 256           // downsampled H and W
#define IN_W 512
#define TILE_W (HW + 2 * RAD)   // 270
#define TILE_PITCH 272          // 1088 B rows: keeps float4 reads 16B-aligned
#define PLANE (HW * HW)         // 65536

typedef float vf4 __attribute__((ext_vector_type(4)));

__global__ __launch_bounds__(256) void adj_kernel(const float* __restrict__ in,
                                                  float* __restrict__ out) {
    __shared__ float smem[KS][TILE_PITCH];

    const int y   = blockIdx.x;   // output row 0..255
    const int b   = blockIdx.y;   // batch 0..7
    const int tid = threadIdx.x;

    const float* inb = in + (size_t)b * (IN_W * IN_W);

    // Stage 15 downsampled rows (y-7 .. y+7) x full pitch, zero-padded OOB.
    #pragma unroll
    for (int r = 0; r < KS; ++r) {
        const int gy = y - RAD + r;           // downsampled row index
        for (int c = tid; c < TILE_PITCH; c += 256) {
            const int gx = c - RAD;           // downsampled col index
            float v = 0.0f;
            if ((unsigned)gy < HW && (unsigned)gx < HW) {
                v = inb[(size_t)(2 * gy) * IN_W + 2 * gx];
            }
            smem[r][c] = v;
        }
    }
    __syncthreads();

    const int wv   = tid >> 6;    // wave 0..3
    const int lane = tid & 63;
    const int x    = lane * 4;    // this lane's 4 output columns x..x+3

    // own segment ids (center of the window)
    const float s0 = smem[RAD][x + RAD + 0];
    const float s1 = smem[RAD][x + RAD + 1];
    const float s2 = smem[RAD][x + RAD + 2];
    const float s3 = smem[RAD][x + RAD + 3];

    float* base = out + (size_t)b * (KS * KS * (size_t)PLANE) + (size_t)y * HW + x;

    // wave w handles kernel rows r = w, w+4, w+8, w+12
    for (int r = wv; r < KS; r += 4) {
        const float* rowp = &smem[r][x];
        // 20-float sliding window, cols x .. x+19 (need up to x+17)
        vf4 w0 = *(const vf4*)(rowp + 0);
        vf4 w1 = *(const vf4*)(rowp + 4);
        vf4 w2 = *(const vf4*)(rowp + 8);
        vf4 w3 = *(const vf4*)(rowp + 12);
        vf4 w4 = *(const vf4*)(rowp + 16);
        float win[20] = { w0.x, w0.y, w0.z, w0.w,
                          w1.x, w1.y, w1.z, w1.w,
                          w2.x, w2.y, w2.z, w2.w,
                          w3.x, w3.y, w3.z, w3.w,
                          w4.x, w4.y, w4.z, w4.w };
        float* op = base + (size_t)(r * KS) * PLANE;
        #pragma unroll
        for (int dc = 0; dc < KS; ++dc) {
            vf4 v;
            v.x = (s0 == win[dc + 0]) ? 1.0f : 0.0f;
            v.y = (s1 == win[dc + 1]) ? 1.0f : 0.0f;
            v.z = (s2 == win[dc + 2]) ? 1.0f : 0.0f;
            v.w = (s3 == win[dc + 3]) ? 1.0f : 0.0f;
            __builtin_nontemporal_store(v, (vf4*)op);
            op += PLANE;
        }
    }
}

extern "C" void kernel_launch(void* const* d_in, const int* in_sizes, int n_in,
                              void* d_out, int out_size, void* d_ws, size_t ws_size,
                              hipStream_t stream) {
    const float* segments = (const float*)d_in[0];
    float* out = (float*)d_out;
    dim3 grid(HW, 8);   // (y, b)
    dim3 block(256);
    adj_kernel<<<grid, block, 0, stream>>>(segments, out);
}